// Round 1
// baseline (579.729 us; speedup 1.0000x reference)
//
#include <hip/hip_runtime.h>
#include <math.h>

#define BB 32
#define LL 50
#define CC 80
#define AA 3
#define IMGF 480.0f
#define ROWS_TOTAL 14175              // 60*60*3 + 30*30*3 + 15*15*3
#define BOX_OFF 1L
#define SCORE_OFF (1L + (long)BB * ROWS_TOTAL * 4)   // 1814401

__device__ __forceinline__ float sigmoidf_(float x) { return 1.0f / (1.0f + __expf(-x)); }

// ---------------------------------------------------------------------------
// prep: per (level, b, t) GT record -> matched cell index (within batch/level)
// and the adjusted-target 5-vector. Also zeroes the loss accumulator.
// ---------------------------------------------------------------------------
__global__ void prep_kernel(const float* __restrict__ gt,
                            const float* __restrict__ anchors,
                            int* __restrict__ cells,
                            float* __restrict__ adjs,
                            float* __restrict__ out)
{
    int idx = blockIdx.x * blockDim.x + threadIdx.x;
    if (idx == 0) out[0] = 0.0f;
    if (idx >= 3 * BB * LL) return;
    int t   = idx % LL;
    int b   = (idx / LL) % BB;
    int lvl = idx / (LL * BB);
    int W = (lvl == 0) ? 60 : (lvl == 1) ? 30 : 15;   // H == W
    float Wf = (float)W;

    const float* g = gt + (b * LL + t) * 5;
    float x = g[0], y = g[1], wd = g[2], ht = g[3], cls = g[4];
    float bx = x * Wf, by = y * Wf, bw = wd * Wf, bh = ht * Wf;
    bool valid = bw > 0.0f;
    int j = (int)floorf(bx); j = min(max(j, 0), W - 1);
    int i = (int)floorf(by); i = min(max(i, 0), W - 1);

    // anchor argmax (co-centered IoU); first max wins like jnp.argmax
    float best = -1.0f; int k = 0; float kaw = 1.0f, kah = 1.0f;
#pragma unroll
    for (int kk = 0; kk < AA; ++kk) {
        float aw = anchors[kk * 2 + 0] * Wf;
        float ah = anchors[kk * 2 + 1] * Wf;
        float inter = fminf(bw, aw) * fminf(bh, ah);
        float iou = inter / (bw * bh + aw * ah - inter + 1e-9f);
        if (iou > best) { best = iou; k = kk; kaw = aw; kah = ah; }
    }
    cells[idx] = valid ? ((i * W + j) * AA + k) : -1;
    float* ad = adjs + (long)idx * 5;
    if (valid) {
        ad[0] = bx - (float)j;
        ad[1] = by - (float)i;
        ad[2] = logf(bw / kaw);
        ad[3] = logf(bh / kah);
        ad[4] = cls;
    } else {
        ad[0] = 0.f; ad[1] = 0.f; ad[2] = 0.f; ad[3] = 0.f; ad[4] = 0.f;
    }
}

// ---------------------------------------------------------------------------
// level kernel: 16 threads per prediction cell (b,h,w,a). Computes head
// decode, softmax, IoU-ignore mask vs 50 GT, all 4 loss terms, and writes
// boxes/scores outputs.
// ---------------------------------------------------------------------------
__global__ __launch_bounds__(256) void level_kernel(
    const float* __restrict__ preds,
    const float* __restrict__ gt,
    const float* __restrict__ anchors,
    const int* __restrict__ cells,
    const float* __restrict__ adjs,
    float* __restrict__ out,
    int H, int W, int rowoff, int lvloff)
{
    int tid  = blockIdx.x * blockDim.x + threadIdx.x;
    int cell = tid >> 4;        // grids are exact multiples of 16 cells/block
    int sub  = tid & 15;

    int a = cell % AA;
    int tmp = cell / AA;
    int w = tmp % W; tmp /= W;
    int h = tmp % H;
    int b = tmp / H;
    int local_cell = (h * W + w) * AA + a;

    long base = (long)cell * (5 + CC);

    // broadcast f0..f4 (x, y, w, h, conf logits)
    float fv = (sub < 5) ? preds[base + sub] : 0.0f;
    float f0 = __shfl(fv, 0, 16);
    float f1 = __shfl(fv, 1, 16);
    float f2 = __shfl(fv, 2, 16);
    float f3 = __shfl(fv, 3, 16);
    float f4 = __shfl(fv, 4, 16);

    // class logits: thread sub handles classes sub + 16*i
    float v0 = preds[base + 5 + sub];
    float v1 = preds[base + 5 + sub + 16];
    float v2 = preds[base + 5 + sub + 32];
    float v3 = preds[base + 5 + sub + 48];
    float v4 = preds[base + 5 + sub + 64];
    float m = fmaxf(fmaxf(fmaxf(v0, v1), fmaxf(v2, v3)), v4);
#pragma unroll
    for (int off = 8; off; off >>= 1) m = fmaxf(m, __shfl_xor(m, off, 16));
    float e0 = __expf(v0 - m), e1 = __expf(v1 - m), e2 = __expf(v2 - m),
          e3 = __expf(v3 - m), e4 = __expf(v4 - m);
    float s = e0 + e1 + e2 + e3 + e4;
#pragma unroll
    for (int off = 8; off; off >>= 1) s += __shfl_xor(s, off, 16);
    float inv = 1.0f / s;

    float conf = sigmoidf_(f4);
    float ancw = anchors[a * 2 + 0], anch = anchors[a * 2 + 1];
    float bxs = sigmoidf_(f0), bys = sigmoidf_(f1);
    float px = (bxs + (float)w) / (float)W;
    float py = (bys + (float)h) / (float)H;
    float pw = __expf(f2) * ancw;     // anchors_l / conv == raw anchors
    float ph = __expf(f3) * anch;
    float pminx = px - 0.5f * pw, pmaxx = px + 0.5f * pw;
    float pminy = py - 0.5f * ph, pmaxy = py + 0.5f * ph;
    float parea = pw * ph;

    // IoU vs 50 GT (split over 16 threads) + match search (last-write-wins)
    const float* gtb   = gt + (long)b * LL * 5;
    const int* cellsb  = cells + lvloff + b * LL;
    float best = 0.0f;
    int wt = -1;
    for (int t = sub; t < LL; t += 16) {
        const float* g = gtb + t * 5;
        float gx = g[0], gy = g[1], gw = g[2], gh = g[3];
        float tminx = gx - 0.5f * gw, tmaxx = gx + 0.5f * gw;
        float tminy = gy - 0.5f * gh, tmaxy = gy + 0.5f * gh;
        float ix = fmaxf(fminf(pmaxx, tmaxx) - fmaxf(pminx, tminx), 0.0f);
        float iy = fmaxf(fminf(pmaxy, tmaxy) - fmaxf(pminy, tminy), 0.0f);
        float inter = ix * iy;
        float iou = inter / (parea + gw * gh - inter + 1e-9f);
        best = fmaxf(best, iou);
        if (cellsb[t] == local_cell) wt = t;
    }
#pragma unroll
    for (int off = 8; off; off >>= 1) {
        best = fmaxf(best, __shfl_xor(best, off, 16));
        wt   = max(wt, __shfl_xor(wt, off, 16));
    }
    float obj_det = (best > 0.6f) ? 1.0f : 0.0f;
    bool matched = (wt >= 0);

    // ---- outputs ----
    int row = rowoff + local_cell;
    long sbase = SCORE_OFF + ((long)b * ROWS_TOTAL + row) * CC;
    out[sbase + sub]      = conf * e0 * inv;
    out[sbase + sub + 16] = conf * e1 * inv;
    out[sbase + sub + 32] = conf * e2 * inv;
    out[sbase + sub + 48] = conf * e3 * inv;
    out[sbase + sub + 64] = conf * e4 * inv;
    if (sub < 4) {
        float comp = (sub == 0) ? pminx * IMGF
                   : (sub == 1) ? pminy * IMGF
                   : (sub == 2) ? pmaxx * IMGF
                   :              pmaxy * IMGF;
        out[BOX_OFF + ((long)b * ROWS_TOTAL + row) * 4 + sub] = comp;
    }

    // ---- loss ----
    float partial = 0.0f;
    if (matched) {
        const float* ad = adjs + (long)(lvloff + b * LL + wt) * 5;
        int label = (int)ad[4];
        float d;
        d = ((sub      == label) ? 1.0f : 0.0f) - e0 * inv; partial += d * d;
        d = ((sub + 16 == label) ? 1.0f : 0.0f) - e1 * inv; partial += d * d;
        d = ((sub + 32 == label) ? 1.0f : 0.0f) - e2 * inv; partial += d * d;
        d = ((sub + 48 == label) ? 1.0f : 0.0f) - e3 * inv; partial += d * d;
        d = ((sub + 64 == label) ? 1.0f : 0.0f) - e4 * inv; partial += d * d;
        if (sub == 0) {
            float c0 = ad[0] - bxs, c1 = ad[1] - bys;
            float c2 = ad[2] - f2,  c3 = ad[3] - f3;
            partial += c0 * c0 + c1 * c1 + c2 * c2 + c3 * c3;   // coord
            float u = 1.0f - conf;
            partial += 5.0f * u * u;                            // obj
        }
    } else if (sub == 0) {
        partial += (1.0f - obj_det) * conf * conf;              // noobj
    }

    // block reduction -> one atomicAdd
    float vsum = partial;
#pragma unroll
    for (int off = 32; off; off >>= 1) vsum += __shfl_xor(vsum, off, 64);
    __shared__ float red[4];
    int wave = threadIdx.x >> 6;
    int lane = threadIdx.x & 63;
    if (lane == 0) red[wave] = vsum;
    __syncthreads();
    if (threadIdx.x == 0) {
        atomicAdd(out, 0.5f * (red[0] + red[1] + red[2] + red[3]));
    }
}

extern "C" void kernel_launch(void* const* d_in, const int* in_sizes, int n_in,
                              void* d_out, int out_size, void* d_ws, size_t ws_size,
                              hipStream_t stream)
{
    const float* preds0  = (const float*)d_in[0];
    const float* preds1  = (const float*)d_in[1];
    const float* preds2  = (const float*)d_in[2];
    const float* gt      = (const float*)d_in[3];
    const float* anchors = (const float*)d_in[4];
    float* out = (float*)d_out;

    int*   cells = (int*)d_ws;
    float* adjs  = (float*)((char*)d_ws + 3 * BB * LL * sizeof(int));

    prep_kernel<<<(3 * BB * LL + 255) / 256, 256, 0, stream>>>(gt, anchors, cells, adjs, out);

    // 16 threads/cell, 256 threads/block -> 16 cells/block; all exact multiples
    int c0 = BB * 60 * 60 * AA;   // 345600
    int c1 = BB * 30 * 30 * AA;   // 86400
    int c2 = BB * 15 * 15 * AA;   // 21600
    level_kernel<<<c0 / 16, 256, 0, stream>>>(preds0, gt, anchors, cells, adjs, out, 60, 60, 0,     0);
    level_kernel<<<c1 / 16, 256, 0, stream>>>(preds1, gt, anchors, cells, adjs, out, 30, 30, 10800, BB * LL);
    level_kernel<<<c2 / 16, 256, 0, stream>>>(preds2, gt, anchors, cells, adjs, out, 15, 15, 13500, 2 * BB * LL);
}

// Round 2
// 362.726 us; speedup vs baseline: 1.5983x; 1.5983x over previous
//
#include <hip/hip_runtime.h>
#include <math.h>

#define BB 32
#define LL 50
#define CC 80
#define AA 3
#define IMGF 480.0f
#define ROWS_TOTAL 14175              // 60*60*3 + 30*30*3 + 15*15*3
#define BOX_OFF 1L
#define SCORE_OFF (1L + (long)BB * ROWS_TOTAL * 4)   // 1814401

// per-image chunk counts (16 cells per block)
#define CH0 675   // 10800/16
#define CH1 169   // ceil(2700/16)
#define CH2 43    // ceil(675/16)
#define NPART (32 * (CH0 + CH1 + CH2))   // 28384 block partials

#define RECW 12   // floats per GT record

__device__ __forceinline__ float sigmoidf_(float x) { return 1.0f / (1.0f + __expf(-x)); }

// ---------------------------------------------------------------------------
// prep: per (level, b, t) GT record:
// [0..3] tminx,tminy,tmaxx,tmaxy (normalized)  [4] area  [5] cell (float, -1 invalid)
// [6..9] adj x,y,logw,logh  [10] class  [11] pad
// ---------------------------------------------------------------------------
__global__ void prep_kernel(const float* __restrict__ gt,
                            const float* __restrict__ anchors,
                            float* __restrict__ gtrec)
{
    int idx = blockIdx.x * blockDim.x + threadIdx.x;
    if (idx >= 3 * BB * LL) return;
    int t   = idx % LL;
    int b   = (idx / LL) % BB;
    int lvl = idx / (LL * BB);
    int W = (lvl == 0) ? 60 : (lvl == 1) ? 30 : 15;   // H == W
    float Wf = (float)W;

    const float* g = gt + (b * LL + t) * 5;
    float x = g[0], y = g[1], wd = g[2], ht = g[3], cls = g[4];
    float bx = x * Wf, by = y * Wf, bw = wd * Wf, bh = ht * Wf;
    bool valid = bw > 0.0f;
    int j = (int)floorf(bx); j = min(max(j, 0), W - 1);
    int i = (int)floorf(by); i = min(max(i, 0), W - 1);

    float best = -1.0f; int k = 0; float kaw = 1.0f, kah = 1.0f;
#pragma unroll
    for (int kk = 0; kk < AA; ++kk) {
        float aw = anchors[kk * 2 + 0] * Wf;
        float ah = anchors[kk * 2 + 1] * Wf;
        float inter = fminf(bw, aw) * fminf(bh, ah);
        float iou = inter / (bw * bh + aw * ah - inter + 1e-9f);
        if (iou > best) { best = iou; k = kk; kaw = aw; kah = ah; }
    }

    float* rec = gtrec + (long)idx * RECW;
    rec[0] = x - 0.5f * wd;
    rec[1] = y - 0.5f * ht;
    rec[2] = x + 0.5f * wd;
    rec[3] = y + 0.5f * ht;
    rec[4] = wd * ht;
    rec[5] = valid ? (float)((i * W + j) * AA + k) : -1.0f;
    if (valid) {
        rec[6] = bx - (float)j;
        rec[7] = by - (float)i;
        rec[8] = logf(bw / kaw);
        rec[9] = logf(bh / kah);
    } else {
        rec[6] = 0.f; rec[7] = 0.f; rec[8] = 0.f; rec[9] = 0.f;
    }
    rec[10] = cls;
    rec[11] = 0.f;
}

// ---------------------------------------------------------------------------
// level kernel: 16 cells per block (one image per block), 16 threads/cell.
// Preds slab + GT records staged in LDS. Block partial loss -> ws.
// ---------------------------------------------------------------------------
__global__ __launch_bounds__(256) void level_kernel(
    const float* __restrict__ preds,
    const float* __restrict__ anchors,
    const float* __restrict__ gtrec,
    float* __restrict__ partials,
    float* __restrict__ out,
    int W, int cells_per_b, int chunks, int rowoff, int lvloff, int pbase)
{
    __shared__ float s_preds[16 * 88];       // stride 88 to break bank patterns
    __shared__ float s_gt[LL * RECW];
    __shared__ float red[4];

    int b     = blockIdx.x / chunks;
    int chunk = blockIdx.x - b * chunks;
    int cell0 = chunk * 16;
    int ncell = min(16, cells_per_b - cell0);

    int tid = threadIdx.x;

    // stage preds slab (coalesced global, padded LDS)
    const float* gp = preds + ((long)b * cells_per_b + cell0) * (5 + CC);
    int nelem = ncell * (5 + CC);
    for (int i = tid; i < nelem; i += 256) {
        int g = i / 85;
        s_preds[g * 88 + (i - g * 85)] = gp[i];
    }
    // stage GT records for this image/level
    const float* gr = gtrec + (long)(lvloff + b * LL) * RECW;
    for (int i = tid; i < LL * RECW; i += 256) s_gt[i] = gr[i];
    __syncthreads();

    int g   = tid >> 4;
    int sub = tid & 15;
    int cell = cell0 + g;                 // local cell within image
    bool cvalid = cell < cells_per_b;

    int a = cell % AA;
    int tmp = cell / AA;
    int w = tmp % W;
    int h = tmp / W;

    const float* sp = s_preds + g * 88;
    float f0 = sp[0], f1 = sp[1], f2 = sp[2], f3 = sp[3], f4 = sp[4];

    float v0 = sp[5 + sub];
    float v1 = sp[5 + sub + 16];
    float v2 = sp[5 + sub + 32];
    float v3 = sp[5 + sub + 48];
    float v4 = sp[5 + sub + 64];
    float m = fmaxf(fmaxf(fmaxf(v0, v1), fmaxf(v2, v3)), v4);
#pragma unroll
    for (int off = 8; off; off >>= 1) m = fmaxf(m, __shfl_xor(m, off, 16));
    float e0 = __expf(v0 - m), e1 = __expf(v1 - m), e2 = __expf(v2 - m),
          e3 = __expf(v3 - m), e4 = __expf(v4 - m);
    float s = e0 + e1 + e2 + e3 + e4;
#pragma unroll
    for (int off = 8; off; off >>= 1) s += __shfl_xor(s, off, 16);
    float inv = 1.0f / s;

    float conf = sigmoidf_(f4);
    float ancw = anchors[a * 2 + 0], anch = anchors[a * 2 + 1];
    float bxs = sigmoidf_(f0), bys = sigmoidf_(f1);
    float invW = 1.0f / (float)W;
    float px = (bxs + (float)w) * invW;
    float py = (bys + (float)h) * invW;
    float pw = __expf(f2) * ancw;
    float ph = __expf(f3) * anch;
    float pminx = px - 0.5f * pw, pmaxx = px + 0.5f * pw;
    float pminy = py - 0.5f * ph, pmaxy = py + 0.5f * ph;
    float parea = pw * ph;

    // IoU vs 50 GT from LDS + match search
    float best = 0.0f;
    int wt = -1;
    float fcell = (float)cell;
    for (int t = sub; t < LL; t += 16) {
        const float* rec = s_gt + t * RECW;
        float tminx = rec[0], tminy = rec[1], tmaxx = rec[2], tmaxy = rec[3];
        float tarea = rec[4], rc = rec[5];
        float ix = fmaxf(fminf(pmaxx, tmaxx) - fmaxf(pminx, tminx), 0.0f);
        float iy = fmaxf(fminf(pmaxy, tmaxy) - fmaxf(pminy, tminy), 0.0f);
        float inter = ix * iy;
        float iou = inter / (parea + tarea - inter + 1e-9f);
        best = fmaxf(best, iou);
        if (rc == fcell) wt = t;
    }
#pragma unroll
    for (int off = 8; off; off >>= 1) {
        best = fmaxf(best, __shfl_xor(best, off, 16));
        wt   = max(wt, __shfl_xor(wt, off, 16));
    }
    float obj_det = (best > 0.6f) ? 1.0f : 0.0f;
    bool matched = (wt >= 0);

    float partial = 0.0f;
    if (cvalid) {
        // outputs
        int row = rowoff + cell;
        long rb = (long)b * ROWS_TOTAL + row;
        long sbase = SCORE_OFF + rb * CC;
        out[sbase + sub]      = conf * e0 * inv;
        out[sbase + sub + 16] = conf * e1 * inv;
        out[sbase + sub + 32] = conf * e2 * inv;
        out[sbase + sub + 48] = conf * e3 * inv;
        out[sbase + sub + 64] = conf * e4 * inv;
        if (sub < 4) {
            float comp = (sub == 0) ? pminx * IMGF
                       : (sub == 1) ? pminy * IMGF
                       : (sub == 2) ? pmaxx * IMGF
                       :              pmaxy * IMGF;
            out[BOX_OFF + rb * 4 + sub] = comp;
        }

        // loss
        if (matched) {
            const float* rec = s_gt + wt * RECW;
            int label = (int)rec[10];
            float d;
            d = ((sub      == label) ? 1.0f : 0.0f) - e0 * inv; partial += d * d;
            d = ((sub + 16 == label) ? 1.0f : 0.0f) - e1 * inv; partial += d * d;
            d = ((sub + 32 == label) ? 1.0f : 0.0f) - e2 * inv; partial += d * d;
            d = ((sub + 48 == label) ? 1.0f : 0.0f) - e3 * inv; partial += d * d;
            d = ((sub + 64 == label) ? 1.0f : 0.0f) - e4 * inv; partial += d * d;
            if (sub == 0) {
                float c0 = rec[6] - bxs, c1 = rec[7] - bys;
                float c2 = rec[8] - f2,  c3 = rec[9] - f3;
                partial += c0 * c0 + c1 * c1 + c2 * c2 + c3 * c3;   // coord
                float u = 1.0f - conf;
                partial += 5.0f * u * u;                            // obj
            }
        } else if (sub == 0) {
            partial += (1.0f - obj_det) * conf * conf;              // noobj
        }
    }

    // block reduction -> one partial store (no atomics)
    float vsum = partial;
#pragma unroll
    for (int off = 32; off; off >>= 1) vsum += __shfl_xor(vsum, off, 64);
    int wave = threadIdx.x >> 6;
    int lane = threadIdx.x & 63;
    if (lane == 0) red[wave] = vsum;
    __syncthreads();
    if (threadIdx.x == 0) {
        partials[pbase + blockIdx.x] = 0.5f * (red[0] + red[1] + red[2] + red[3]);
    }
}

__global__ void reduce_kernel(const float* __restrict__ partials,
                              float* __restrict__ out)
{
    __shared__ float red[4];
    float s = 0.0f;
    for (int i = threadIdx.x; i < NPART; i += 256) s += partials[i];
#pragma unroll
    for (int off = 32; off; off >>= 1) s += __shfl_xor(s, off, 64);
    int wave = threadIdx.x >> 6;
    if ((threadIdx.x & 63) == 0) red[wave] = s;
    __syncthreads();
    if (threadIdx.x == 0) out[0] = red[0] + red[1] + red[2] + red[3];
}

extern "C" void kernel_launch(void* const* d_in, const int* in_sizes, int n_in,
                              void* d_out, int out_size, void* d_ws, size_t ws_size,
                              hipStream_t stream)
{
    const float* preds0  = (const float*)d_in[0];
    const float* preds1  = (const float*)d_in[1];
    const float* preds2  = (const float*)d_in[2];
    const float* gt      = (const float*)d_in[3];
    const float* anchors = (const float*)d_in[4];
    float* out = (float*)d_out;

    float* gtrec    = (float*)d_ws;                                   // 4800*12 floats
    float* partials = gtrec + 3 * BB * LL * RECW;                     // 28384 floats

    prep_kernel<<<(3 * BB * LL + 255) / 256, 256, 0, stream>>>(gt, anchors, gtrec);

    level_kernel<<<32 * CH0, 256, 0, stream>>>(preds0, anchors, gtrec, partials, out,
                                               60, 10800, CH0, 0,     0,          0);
    level_kernel<<<32 * CH1, 256, 0, stream>>>(preds1, anchors, gtrec, partials, out,
                                               30, 2700,  CH1, 10800, BB * LL,    32 * CH0);
    level_kernel<<<32 * CH2, 256, 0, stream>>>(preds2, anchors, gtrec, partials, out,
                                               15, 675,   CH2, 13500, 2 * BB * LL, 32 * (CH0 + CH1));

    reduce_kernel<<<1, 256, 0, stream>>>(partials, out);
}

// Round 3
// 319.385 us; speedup vs baseline: 1.8151x; 1.1357x over previous
//
#include <hip/hip_runtime.h>
#include <math.h>

#define BB 32
#define LL 50
#define CC 80
#define AA 3
#define IMGF 480.0f
#define ROWS_TOTAL 14175
#define BOX_OFF 1L
#define SCORE_OFF (1L + (long)BB * ROWS_TOTAL * 4)   // 1814401 floats

// cells per image per level
#define CB0 10800
#define CB1 2700
#define CB2 675
#define NCELLS (BB * (CB0 + CB1 + CB2))   // 453600

// 64 cells per block (256 threads, 4 threads/cell)
#define CH0 169
#define CH1 43
#define CH2 11
#define BLK0 (BB * CH0)   // 5408
#define BLK1 (BB * CH1)   // 1376
#define BLK2 (BB * CH2)   // 352
#define NBLK (BLK0 + BLK1 + BLK2)   // 7136

// workspace layout (byte offsets, all 16B-aligned)
#define WS_MATCH 0                         // int[453600]
#define WS_CREC  (NCELLS * 4)              // float[32*50*8] compacted GT records
#define WS_NVAL  (WS_CREC + BB * LL * 8 * 4)   // int[32]
#define WS_ADJ   (WS_NVAL + 128)           // float[3*32*50*5] adjusted targets
#define WS_PART  (WS_ADJ + 3 * BB * LL * 5 * 4) // float[NBLK] block partials

// ---------------------------------------------------------------------------
// init: fill match table with -1; compact valid GT boxes per image
// record: [tminx, tminy, tmaxx, tmaxy, 0.6*area, pad, pad, pad]  (normalized)
// ---------------------------------------------------------------------------
__global__ void init_kernel(const float* __restrict__ gt, char* __restrict__ ws)
{
    int idx = blockIdx.x * blockDim.x + threadIdx.x;
    int4* mt = (int4*)(ws + WS_MATCH);
    if (idx < NCELLS / 4) mt[idx] = make_int4(-1, -1, -1, -1);
    if (blockIdx.x == 0 && threadIdx.x < BB) {
        int b = threadIdx.x;
        float* cr = (float*)(ws + WS_CREC) + b * LL * 8;
        int n = 0;
        for (int t = 0; t < LL; ++t) {
            const float* g = gt + (b * LL + t) * 5;
            float x = g[0], y = g[1], w = g[2], h = g[3];
            if (w > 0.0f) {
                float* r = cr + n * 8;
                r[0] = x - 0.5f * w; r[1] = y - 0.5f * h;
                r[2] = x + 0.5f * w; r[3] = y + 0.5f * h;
                r[4] = 0.6f * (w * h); r[5] = 0.f; r[6] = 0.f; r[7] = 0.f;
                n++;
            }
        }
        ((int*)(ws + WS_NVAL))[b] = n;
    }
}

// ---------------------------------------------------------------------------
// prep: per (level,b,t) valid GT: adjusted targets + atomicMax scatter into
// the match table (max t == last-write-wins of the reference scatter).
// ---------------------------------------------------------------------------
__global__ void prep_kernel(const float* __restrict__ gt,
                            const float* __restrict__ anchors,
                            char* __restrict__ ws)
{
    int idx = blockIdx.x * blockDim.x + threadIdx.x;
    if (idx >= 3 * BB * LL) return;
    int t   = idx % LL;
    int b   = (idx / LL) % BB;
    int lvl = idx / (LL * BB);
    int W       = (lvl == 0) ? 60 : (lvl == 1) ? 30 : 15;
    int cells_b = (lvl == 0) ? CB0 : (lvl == 1) ? CB1 : CB2;
    int cellof  = (lvl == 0) ? 0 : (lvl == 1) ? BB * CB0 : BB * (CB0 + CB1);
    float Wf = (float)W;

    const float* g = gt + (b * LL + t) * 5;
    float x = g[0], y = g[1], wd = g[2], ht = g[3], cls = g[4];
    if (wd <= 0.0f) return;
    float bx = x * Wf, by = y * Wf, bw = wd * Wf, bh = ht * Wf;
    int j = min(max((int)floorf(bx), 0), W - 1);
    int i = min(max((int)floorf(by), 0), W - 1);

    float best = -1.0f; int k = 0; float kaw = 1.0f, kah = 1.0f;
#pragma unroll
    for (int kk = 0; kk < AA; ++kk) {
        float aw = anchors[kk * 2 + 0] * Wf;
        float ah = anchors[kk * 2 + 1] * Wf;
        float inter = fminf(bw, aw) * fminf(bh, ah);
        float iou = inter / (bw * bh + aw * ah - inter + 1e-9f);
        if (iou > best) { best = iou; k = kk; kaw = aw; kah = ah; }
    }
    int cell = (i * W + j) * AA + k;
    atomicMax((int*)(ws + WS_MATCH) + cellof + b * cells_b + cell, t);
    float* ad = (float*)(ws + WS_ADJ) + ((lvl * BB + b) * LL + t) * 5;
    ad[0] = bx - (float)j;
    ad[1] = by - (float)i;
    ad[2] = logf(bw / kaw);
    ad[3] = logf(bh / kah);
    ad[4] = cls;
}

// ---------------------------------------------------------------------------
// main: all three levels. 4 threads/cell, 64 cells/block. No LDS staging,
// no softmax max-subtraction, division-free ignore test, match table lookup.
// ---------------------------------------------------------------------------
__global__ __launch_bounds__(256) void main_kernel(
    const float* __restrict__ preds0,
    const float* __restrict__ preds1,
    const float* __restrict__ preds2,
    const float* __restrict__ anchors,
    const char* __restrict__ wsc,
    float* __restrict__ partials,
    float* __restrict__ out)
{
    const int*   matchtbl = (const int*)(wsc + WS_MATCH);
    const float* crec     = (const float*)(wsc + WS_CREC);
    const int*   nval     = (const int*)(wsc + WS_NVAL);
    const float* adj      = (const float*)(wsc + WS_ADJ);

    int bid = blockIdx.x;
    const float* preds; int W, cells_b, rowoff, cellof, b, chunk, lvl;
    float invW; unsigned Wmagic;
    if (bid < BLK0) {
        lvl = 0; preds = preds0; W = 60; invW = 1.0f / 60.0f; Wmagic = 71582789u;
        cells_b = CB0; rowoff = 0; cellof = 0;
        b = bid / CH0; chunk = bid - b * CH0;
    } else if (bid < BLK0 + BLK1) {
        int inner = bid - BLK0;
        lvl = 1; preds = preds1; W = 30; invW = 1.0f / 30.0f; Wmagic = 143165577u;
        cells_b = CB1; rowoff = CB0; cellof = BB * CB0;
        b = inner / CH1; chunk = inner - b * CH1;
    } else {
        int inner = bid - BLK0 - BLK1;
        lvl = 2; preds = preds2; W = 15; invW = 1.0f / 15.0f; Wmagic = 286331154u;
        cells_b = CB2; rowoff = CB0 + CB1; cellof = BB * (CB0 + CB1);
        b = inner / CH2; chunk = inner - b * CH2;
    }

    int tid = threadIdx.x;
    int g   = tid >> 2;
    int sub = tid & 3;
    int cell = chunk * 64 + g;
    bool cvalid = cell < cells_b;
    int cc = cvalid ? cell : (cells_b - 1);

    // decode (a, w, h) from cc
    int t1 = cc / 3;
    int a  = cc - t1 * 3;
    int h  = (int)__umulhi((unsigned)t1, Wmagic);
    int w  = t1 - h * W;

    long pbase = ((long)b * cells_b + cc) * 85;
    const float* p = preds + pbase;
    float f0 = p[0], f1 = p[1], f2 = p[2], f3 = p[3], f4 = p[4];

    // class logits: thread owns classes 16k + 4*sub + j  (k=0..4, j=0..3)
    const float* pc = p + 5 + 4 * sub;
    float4 q0 = *(const float4*)(pc);
    float4 q1 = *(const float4*)(pc + 16);
    float4 q2 = *(const float4*)(pc + 32);
    float4 q3 = *(const float4*)(pc + 48);
    float4 q4 = *(const float4*)(pc + 64);
    q0.x = __expf(q0.x); q0.y = __expf(q0.y); q0.z = __expf(q0.z); q0.w = __expf(q0.w);
    q1.x = __expf(q1.x); q1.y = __expf(q1.y); q1.z = __expf(q1.z); q1.w = __expf(q1.w);
    q2.x = __expf(q2.x); q2.y = __expf(q2.y); q2.z = __expf(q2.z); q2.w = __expf(q2.w);
    q3.x = __expf(q3.x); q3.y = __expf(q3.y); q3.z = __expf(q3.z); q3.w = __expf(q3.w);
    q4.x = __expf(q4.x); q4.y = __expf(q4.y); q4.z = __expf(q4.z); q4.w = __expf(q4.w);
    float s = (q0.x + q0.y + q0.z + q0.w) + (q1.x + q1.y + q1.z + q1.w)
            + (q2.x + q2.y + q2.z + q2.w) + (q3.x + q3.y + q3.z + q3.w)
            + (q4.x + q4.y + q4.z + q4.w);
    s += __shfl_xor(s, 1);
    s += __shfl_xor(s, 2);
    float invs = __builtin_amdgcn_rcpf(s);

    float conf = __builtin_amdgcn_rcpf(1.0f + __expf(-f4));
    float bxs  = __builtin_amdgcn_rcpf(1.0f + __expf(-f0));
    float bys  = __builtin_amdgcn_rcpf(1.0f + __expf(-f1));
    float ancw = anchors[2 * a], anch = anchors[2 * a + 1];
    float pw = __expf(f2) * ancw;
    float ph = __expf(f3) * anch;
    float px = (bxs + (float)w) * invW;
    float py = (bys + (float)h) * invW;
    float pminx = px - 0.5f * pw, pmaxx = px + 0.5f * pw;
    float pminy = py - 0.5f * ph, pmaxy = py + 0.5f * ph;
    float pa06 = 0.6f * (pw * ph) + 0.6e-9f;

    // ignore test: any IoU > 0.6  <=>  1.6*inter > 0.6*(pa+ta+1e-9)
    int nv = nval[b];
    const float* cb = crec + b * LL * 8;
    float amax = -1.0f;
    for (int t = sub; t < nv; t += 4) {
        const float* r = cb + t * 8;
        float4 tb = *(const float4*)r;
        float ta06 = r[4];
        float ix = fmaxf(fminf(pmaxx, tb.z) - fmaxf(pminx, tb.x), 0.0f);
        float iy = fmaxf(fminf(pmaxy, tb.w) - fmaxf(pminy, tb.y), 0.0f);
        amax = fmaxf(amax, 1.6f * (ix * iy) - (pa06 + ta06));
    }
    unsigned long long bal = __ballot(amax > 0.0f);
    bool objdet = ((bal >> (tid & 60)) & 0xFULL) != 0ULL;

    int wt = matchtbl[cellof + b * cells_b + cc];

    float partial = 0.0f;
    float ci = conf * invs;
    if (cvalid) {
        long rb = (long)b * ROWS_TOTAL + rowoff + cell;
        float* sb = out + SCORE_OFF + rb * CC + 4 * sub;
        float4 o;
        o.x = q0.x * ci; o.y = q0.y * ci; o.z = q0.z * ci; o.w = q0.w * ci; *(float4*)(sb)      = o;
        o.x = q1.x * ci; o.y = q1.y * ci; o.z = q1.z * ci; o.w = q1.w * ci; *(float4*)(sb + 16) = o;
        o.x = q2.x * ci; o.y = q2.y * ci; o.z = q2.z * ci; o.w = q2.w * ci; *(float4*)(sb + 32) = o;
        o.x = q3.x * ci; o.y = q3.y * ci; o.z = q3.z * ci; o.w = q3.w * ci; *(float4*)(sb + 48) = o;
        o.x = q4.x * ci; o.y = q4.y * ci; o.z = q4.z * ci; o.w = q4.w * ci; *(float4*)(sb + 64) = o;
        {
            float comp = (sub == 0) ? pminx : (sub == 1) ? pminy : (sub == 2) ? pmaxx : pmaxy;
            out[BOX_OFF + rb * 4 + sub] = comp * IMGF;
        }

        if (wt >= 0) {
            const float* ar = adj + ((lvl * BB + b) * LL + wt) * 5;
            int label = (int)ar[4];
            int c = 4 * sub;
            float d;
            d = ((c +  0) == label ? 1.0f : 0.0f) - q0.x * invs; partial += d * d;
            d = ((c +  1) == label ? 1.0f : 0.0f) - q0.y * invs; partial += d * d;
            d = ((c +  2) == label ? 1.0f : 0.0f) - q0.z * invs; partial += d * d;
            d = ((c +  3) == label ? 1.0f : 0.0f) - q0.w * invs; partial += d * d;
            d = ((c + 16) == label ? 1.0f : 0.0f) - q1.x * invs; partial += d * d;
            d = ((c + 17) == label ? 1.0f : 0.0f) - q1.y * invs; partial += d * d;
            d = ((c + 18) == label ? 1.0f : 0.0f) - q1.z * invs; partial += d * d;
            d = ((c + 19) == label ? 1.0f : 0.0f) - q1.w * invs; partial += d * d;
            d = ((c + 32) == label ? 1.0f : 0.0f) - q2.x * invs; partial += d * d;
            d = ((c + 33) == label ? 1.0f : 0.0f) - q2.y * invs; partial += d * d;
            d = ((c + 34) == label ? 1.0f : 0.0f) - q2.z * invs; partial += d * d;
            d = ((c + 35) == label ? 1.0f : 0.0f) - q2.w * invs; partial += d * d;
            d = ((c + 48) == label ? 1.0f : 0.0f) - q3.x * invs; partial += d * d;
            d = ((c + 49) == label ? 1.0f : 0.0f) - q3.y * invs; partial += d * d;
            d = ((c + 50) == label ? 1.0f : 0.0f) - q3.z * invs; partial += d * d;
            d = ((c + 51) == label ? 1.0f : 0.0f) - q3.w * invs; partial += d * d;
            d = ((c + 64) == label ? 1.0f : 0.0f) - q4.x * invs; partial += d * d;
            d = ((c + 65) == label ? 1.0f : 0.0f) - q4.y * invs; partial += d * d;
            d = ((c + 66) == label ? 1.0f : 0.0f) - q4.z * invs; partial += d * d;
            d = ((c + 67) == label ? 1.0f : 0.0f) - q4.w * invs; partial += d * d;
            if (sub == 0) {
                float c0 = ar[0] - bxs, c1 = ar[1] - bys;
                float c2 = ar[2] - f2,  c3 = ar[3] - f3;
                partial += c0 * c0 + c1 * c1 + c2 * c2 + c3 * c3;   // coord
                float u = 1.0f - conf;
                partial += 5.0f * u * u;                            // obj
            }
        } else if (sub == 0) {
            partial += (objdet ? 0.0f : 1.0f) * conf * conf;        // noobj
        }
    }

    // block reduction -> one partial store
    float vsum = partial;
#pragma unroll
    for (int off = 32; off; off >>= 1) vsum += __shfl_xor(vsum, off);
    __shared__ float red[4];
    int wave = tid >> 6;
    if ((tid & 63) == 0) red[wave] = vsum;
    __syncthreads();
    if (tid == 0) partials[bid] = 0.5f * (red[0] + red[1] + red[2] + red[3]);
}

__global__ void reduce_kernel(const float* __restrict__ partials,
                              float* __restrict__ out)
{
    __shared__ float red[4];
    float s = 0.0f;
    for (int i = threadIdx.x; i < NBLK; i += 256) s += partials[i];
#pragma unroll
    for (int off = 32; off; off >>= 1) s += __shfl_xor(s, off);
    int wave = threadIdx.x >> 6;
    if ((threadIdx.x & 63) == 0) red[wave] = s;
    __syncthreads();
    if (threadIdx.x == 0) out[0] = red[0] + red[1] + red[2] + red[3];
}

extern "C" void kernel_launch(void* const* d_in, const int* in_sizes, int n_in,
                              void* d_out, int out_size, void* d_ws, size_t ws_size,
                              hipStream_t stream)
{
    const float* preds0  = (const float*)d_in[0];
    const float* preds1  = (const float*)d_in[1];
    const float* preds2  = (const float*)d_in[2];
    const float* gt      = (const float*)d_in[3];
    const float* anchors = (const float*)d_in[4];
    float* out = (float*)d_out;
    char* ws = (char*)d_ws;

    init_kernel<<<(NCELLS / 4 + 255) / 256, 256, 0, stream>>>(gt, ws);
    prep_kernel<<<(3 * BB * LL + 255) / 256, 256, 0, stream>>>(gt, anchors, ws);
    main_kernel<<<NBLK, 256, 0, stream>>>(preds0, preds1, preds2, anchors,
                                          (const char*)ws,
                                          (float*)(ws + WS_PART), out);
    reduce_kernel<<<1, 256, 0, stream>>>((const float*)(ws + WS_PART), out);
}